// Round 5
// baseline (806.458 us; speedup 1.0000x reference)
//
#include <hip/hip_runtime.h>
#include <math.h>

// ---------------------------------------------------------------------------
// EdgeClassifier: 2x SAGEConv(mean) -> per-node MLP -> edge scorer
//  * layer-1 agg: mean commutes with projection -> aggregate raw nf (4-dim)
//  * layer-2 agg: CSR gather of bf16-packed h1 (halved gather traffic)
//  * ST table: bf16, (We1,Wl1)-pair interleaved -> uint4 per lane
//  * edge_k: CSR order, 4 edges/wave x 16 lanes x 4 j/lane (float4 math)
// ---------------------------------------------------------------------------

__device__ __forceinline__ float fast_tanh(float x) {
    x = fminf(fmaxf(x, -15.f), 15.f);
    float e2 = __expf(2.f * x);
    return (e2 - 1.f) * __builtin_amdgcn_rcpf(e2 + 1.f);
}
__device__ __forceinline__ float fast_sigmoid(float x) {
    x = fminf(fmaxf(x, -60.f), 60.f);
    return __builtin_amdgcn_rcpf(1.f + __expf(-x));
}
__device__ __forceinline__ unsigned short f2bf(float f) {   // RNE
    unsigned u = __float_as_uint(f);
    u = u + 0x7FFFu + ((u >> 16) & 1u);
    return (unsigned short)(u >> 16);
}
__device__ __forceinline__ float bflo(unsigned u) { return __uint_as_float(u << 16); }
__device__ __forceinline__ float bfhi(unsigned u) { return __uint_as_float(u & 0xFFFF0000u); }

__global__ void zero_int_k(int* __restrict__ p, int n) {
    int i = blockIdx.x * blockDim.x + threadIdx.x;
    if (i < n) p[i] = 0;
}

__global__ void count_deg_k(const int* __restrict__ dst, int* __restrict__ deg, int E) {
    int i = blockIdx.x * blockDim.x + threadIdx.x;
    if (i < E) atomicAdd(&deg[dst[i]], 1);
}

__global__ void scan1_k(const int* __restrict__ deg, int* __restrict__ off,
                        int* __restrict__ bsum, int N) {
    __shared__ int tmp[256];
    int i = blockIdx.x * 256 + threadIdx.x;
    int v = (i < N) ? deg[i] : 0;
    tmp[threadIdx.x] = v;
    __syncthreads();
#pragma unroll
    for (int s = 1; s < 256; s <<= 1) {
        int t = (threadIdx.x >= s) ? tmp[threadIdx.x - s] : 0;
        __syncthreads();
        tmp[threadIdx.x] += t;
        __syncthreads();
    }
    if (i < N) off[i] = tmp[threadIdx.x] - v;
    if (threadIdx.x == 255) bsum[blockIdx.x] = tmp[255];
}

__global__ void scan2_k(int* __restrict__ bsum, int nb) {
    __shared__ int tmp[512];
    int i = threadIdx.x;
    int v = (i < nb) ? bsum[i] : 0;
    tmp[i] = v;
    __syncthreads();
#pragma unroll
    for (int s = 1; s < 512; s <<= 1) {
        int t = (i >= s) ? tmp[i - s] : 0;
        __syncthreads();
        tmp[i] += t;
        __syncthreads();
    }
    if (i < nb) bsum[i] = tmp[i] - v;
}

__global__ void scan3_k(int* __restrict__ off, const int* __restrict__ bsum,
                        int* __restrict__ cur, int N, int E) {
    int i = blockIdx.x * 256 + threadIdx.x;
    if (i < N) {
        int v = off[i] + bsum[blockIdx.x];
        off[i] = v;
        cur[i] = v;
    }
    if (i == 0) off[N] = E;
}

__global__ void fill_csr_k(const int* __restrict__ src, const int* __restrict__ dst,
                           int* __restrict__ cur, int2* __restrict__ csr, int E) {
    int e = blockIdx.x * blockDim.x + threadIdx.x;
    if (e >= E) return;
    int pos = atomicAdd(&cur[dst[e]], 1);
    csr[pos] = make_int2(src[e], e);
}

// thread per node: agg_nf[n] = mean of nf[csr.x] (4-dim)
__global__ void aggnf_k(const int* __restrict__ off, const int2* __restrict__ csr,
                        const float* __restrict__ nf, float* __restrict__ agg, int N) {
    int n = blockIdx.x * blockDim.x + threadIdx.x;
    if (n >= N) return;
    int s0 = off[n], s1 = off[n + 1];
    float4 a = {0.f, 0.f, 0.f, 0.f};
    int i = s0;
    for (; i + 4 <= s1; i += 4) {
        float4 r0 = ((const float4*)nf)[csr[i].x];
        float4 r1 = ((const float4*)nf)[csr[i + 1].x];
        float4 r2 = ((const float4*)nf)[csr[i + 2].x];
        float4 r3 = ((const float4*)nf)[csr[i + 3].x];
        a.x += r0.x + r1.x + r2.x + r3.x;
        a.y += r0.y + r1.y + r2.y + r3.y;
        a.z += r0.z + r1.z + r2.z + r3.z;
        a.w += r0.w + r1.w + r2.w + r3.w;
    }
    for (; i < s1; ++i) {
        float4 r = ((const float4*)nf)[csr[i].x];
        a.x += r.x; a.y += r.y; a.z += r.z; a.w += r.w;
    }
    float invd = 1.f / fmaxf((float)(s1 - s0), 1.f);
    a.x *= invd; a.y *= invd; a.z *= invd; a.w *= invd;
    ((float4*)agg)[n] = a;
}

// thread = (n, j-pair): h1 fp32 (float2) + packed bf16 copy
__global__ void h1_k(const float* __restrict__ nf, const float* __restrict__ agg,
                     const float* __restrict__ W1s, const float* __restrict__ W1n,
                     const float* __restrict__ b1, float* __restrict__ h1,
                     unsigned* __restrict__ h1b, int N) {
    int t = blockIdx.x * blockDim.x + threadIdx.x;
    if (t >= N * 32) return;
    int n = t >> 5, j = (t & 31) << 1;
    float4 r = ((const float4*)nf)[n];
    float4 a = ((const float4*)agg)[n];
    float v0 = b1[j]
             + r.x * W1s[j] + r.y * W1s[64 + j] + r.z * W1s[128 + j] + r.w * W1s[192 + j]
             + a.x * W1n[j] + a.y * W1n[64 + j] + a.z * W1n[128 + j] + a.w * W1n[192 + j];
    float v1 = b1[j + 1]
             + r.x * W1s[j + 1] + r.y * W1s[65 + j] + r.z * W1s[129 + j] + r.w * W1s[193 + j]
             + a.x * W1n[j + 1] + a.y * W1n[65 + j] + a.z * W1n[129 + j] + a.w * W1n[193 + j];
    v0 = fmaxf(v0, 0.f);
    v1 = fmaxf(v1, 0.f);
    ((float2*)h1)[t] = make_float2(v0, v1);
    h1b[t] = ((unsigned)f2bf(v1) << 16) | (unsigned)f2bf(v0);
}

// one wave per node: aggh1[n] = mean of bf16 h1 rows; 4 rows at a time.
// lane l: g=l>>4 row slot, q=l&15 handles features 4q..4q+3 (uint2 load)
__global__ __launch_bounds__(256, 8)
void gatherh1_k(const int* __restrict__ off, const int2* __restrict__ csr,
                const unsigned* __restrict__ h1b, float* __restrict__ aggh1, int N) {
    int n = blockIdx.x * 4 + (threadIdx.x >> 6);
    if (n >= N) return;
    int l = threadIdx.x & 63;
    int g = l >> 4, q = l & 15;
    int s0 = off[n], s1 = off[n + 1];
    float4 acc = {0.f, 0.f, 0.f, 0.f};
    int i = s0;
    for (; i + 4 <= s1; i += 4) {
        int row = csr[i + g].x;
        uint2 v = *(const uint2*)&h1b[(size_t)row * 32 + q * 2];
        acc.x += bflo(v.x); acc.y += bfhi(v.x);
        acc.z += bflo(v.y); acc.w += bfhi(v.y);
    }
    int rem = s1 - i;
    if (g < rem) {
        int row = csr[i + g].x;
        uint2 v = *(const uint2*)&h1b[(size_t)row * 32 + q * 2];
        acc.x += bflo(v.x); acc.y += bfhi(v.x);
        acc.z += bflo(v.y); acc.w += bfhi(v.y);
    }
#pragma unroll
    for (int m = 16; m <= 32; m <<= 1) {
        acc.x += __shfl_xor(acc.x, m);
        acc.y += __shfl_xor(acc.y, m);
        acc.z += __shfl_xor(acc.z, m);
        acc.w += __shfl_xor(acc.w, m);
    }
    if (l < 16) {
        float invd = 1.f / fmaxf((float)(s1 - s0), 1.f);
        acc.x *= invd; acc.y *= invd; acc.z *= invd; acc.w *= invd;
        *(float4*)&aggh1[(size_t)n * 64 + q * 4] = acc;
    }
}

// h2 = relu(h1@W2s + aggh1@W2n + b2); two-phase LDS reuse
__global__ __launch_bounds__(256, 4)
void gemm2_k(const float* __restrict__ A1, const float* __restrict__ A2,
             const float* __restrict__ W1, const float* __restrict__ W2,
             const float* __restrict__ b, float* __restrict__ C, int M) {
    __shared__ __align__(16) float hT[64][68];
    __shared__ __align__(16) float wt[64][64];
    const int t = threadIdx.x;
    const int m0 = blockIdx.x * 64;
    const int cr = (t & 15) << 2, rr = (t >> 4) << 2;
    float acc[4][4] = {};
    for (int ph = 0; ph < 2; ++ph) {
        const float* A = ph ? A2 : A1;
        const float* W = ph ? W2 : W1;
        if (ph) __syncthreads();
#pragma unroll
        for (int it = 0; it < 16; ++it) {
            int m = it * 4 + (t >> 6), k = t & 63, row = m0 + m;
            hT[k][m] = (row < M) ? A[(size_t)row * 64 + k] : 0.f;
        }
#pragma unroll
        for (int it = 0; it < 16; ++it) {
            int k = it * 4 + (t >> 6), c = t & 63;
            wt[k][c] = W[k * 64 + c];
        }
        __syncthreads();
#pragma unroll 8
        for (int k = 0; k < 64; ++k) {
            float4 a = *(const float4*)&hT[k][rr];
            float4 w = *(const float4*)&wt[k][cr];
            acc[0][0] = fmaf(a.x, w.x, acc[0][0]); acc[0][1] = fmaf(a.x, w.y, acc[0][1]);
            acc[0][2] = fmaf(a.x, w.z, acc[0][2]); acc[0][3] = fmaf(a.x, w.w, acc[0][3]);
            acc[1][0] = fmaf(a.y, w.x, acc[1][0]); acc[1][1] = fmaf(a.y, w.y, acc[1][1]);
            acc[1][2] = fmaf(a.y, w.z, acc[1][2]); acc[1][3] = fmaf(a.y, w.w, acc[1][3]);
            acc[2][0] = fmaf(a.z, w.x, acc[2][0]); acc[2][1] = fmaf(a.z, w.y, acc[2][1]);
            acc[2][2] = fmaf(a.z, w.z, acc[2][2]); acc[2][3] = fmaf(a.z, w.w, acc[2][3]);
            acc[3][0] = fmaf(a.w, w.x, acc[3][0]); acc[3][1] = fmaf(a.w, w.y, acc[3][1]);
            acc[3][2] = fmaf(a.w, w.z, acc[3][2]); acc[3][3] = fmaf(a.w, w.w, acc[3][3]);
        }
    }
#pragma unroll
    for (int i = 0; i < 4; ++i) {
        int row = m0 + rr + i;
        if (row >= M) continue;
        float4 r = {acc[i][0] + b[cr], acc[i][1] + b[cr + 1],
                    acc[i][2] + b[cr + 2], acc[i][3] + b[cr + 3]};
        r.x = fmaxf(r.x, 0.f); r.y = fmaxf(r.y, 0.f);
        r.z = fmaxf(r.z, 0.f); r.w = fmaxf(r.w, 0.f);
        *(float4*)&C[(size_t)row * 64 + cr] = r;
    }
}

// Wbig col c: halves [0,128)=src-part, [128,256)=dst-part; within a half,
// col 2j -> We1 col j, col 2j+1 -> Wl1 col j (rows 0..63 src, 64..127 dst)
__global__ void pack_k(const float* __restrict__ We1, const float* __restrict__ Wl1,
                       float* __restrict__ Wbig) {
    int t = blockIdx.x * 256 + threadIdx.x;
    if (t >= 64 * 256) return;
    int k = t >> 8, c = t & 255;
    int half = c >> 7, cc = c & 127;
    int j = cc >> 1, p = cc & 1;
    const float* W = p ? Wl1 : We1;
    Wbig[t] = W[(half * 64 + k) * 64 + j];
}

// hn = relu(h2@Wnp+bnp) in LDS, then ST(bf16) = hn @ Wbig
__global__ __launch_bounds__(256, 4)
void stgemm_k(const float* __restrict__ h2, const float* __restrict__ Wnp,
              const float* __restrict__ bnp, const float* __restrict__ Wbig,
              unsigned short* __restrict__ ST, int N) {
    __shared__ __align__(16) float hT[64][68];
    __shared__ __align__(16) float wt[64][64];
    const int t = threadIdx.x;
    const int m0 = blockIdx.x * 64;
    const int c0 = blockIdx.y * 64;
    const int cr = (t & 15) << 2, rr = (t >> 4) << 2;
#pragma unroll
    for (int it = 0; it < 16; ++it) {
        int m = it * 4 + (t >> 6), k = t & 63, row = m0 + m;
        hT[k][m] = (row < N) ? h2[(size_t)row * 64 + k] : 0.f;
    }
#pragma unroll
    for (int it = 0; it < 16; ++it) {
        int k = it * 4 + (t >> 6), c = t & 63;
        wt[k][c] = Wnp[k * 64 + c];
    }
    __syncthreads();
    float acc[4][4] = {};
#pragma unroll 8
    for (int k = 0; k < 64; ++k) {
        float4 a = *(const float4*)&hT[k][rr];
        float4 w = *(const float4*)&wt[k][cr];
        acc[0][0] = fmaf(a.x, w.x, acc[0][0]); acc[0][1] = fmaf(a.x, w.y, acc[0][1]);
        acc[0][2] = fmaf(a.x, w.z, acc[0][2]); acc[0][3] = fmaf(a.x, w.w, acc[0][3]);
        acc[1][0] = fmaf(a.y, w.x, acc[1][0]); acc[1][1] = fmaf(a.y, w.y, acc[1][1]);
        acc[1][2] = fmaf(a.y, w.z, acc[1][2]); acc[1][3] = fmaf(a.y, w.w, acc[1][3]);
        acc[2][0] = fmaf(a.z, w.x, acc[2][0]); acc[2][1] = fmaf(a.z, w.y, acc[2][1]);
        acc[2][2] = fmaf(a.z, w.z, acc[2][2]); acc[2][3] = fmaf(a.z, w.w, acc[2][3]);
        acc[3][0] = fmaf(a.w, w.x, acc[3][0]); acc[3][1] = fmaf(a.w, w.y, acc[3][1]);
        acc[3][2] = fmaf(a.w, w.z, acc[3][2]); acc[3][3] = fmaf(a.w, w.w, acc[3][3]);
    }
    __syncthreads();
#pragma unroll
    for (int i = 0; i < 4; ++i)
#pragma unroll
        for (int q = 0; q < 4; ++q)
            hT[cr + q][rr + i] = fmaxf(acc[i][q] + bnp[cr + q], 0.f);
#pragma unroll
    for (int it = 0; it < 16; ++it) {
        int k = it * 4 + (t >> 6), c = t & 63;
        wt[k][c] = Wbig[(size_t)k * 256 + c0 + c];
    }
    __syncthreads();
    float ac2[4][4] = {};
#pragma unroll 8
    for (int k = 0; k < 64; ++k) {
        float4 a = *(const float4*)&hT[k][rr];
        float4 w = *(const float4*)&wt[k][cr];
        ac2[0][0] = fmaf(a.x, w.x, ac2[0][0]); ac2[0][1] = fmaf(a.x, w.y, ac2[0][1]);
        ac2[0][2] = fmaf(a.x, w.z, ac2[0][2]); ac2[0][3] = fmaf(a.x, w.w, ac2[0][3]);
        ac2[1][0] = fmaf(a.y, w.x, ac2[1][0]); ac2[1][1] = fmaf(a.y, w.y, ac2[1][1]);
        ac2[1][2] = fmaf(a.y, w.z, ac2[1][2]); ac2[1][3] = fmaf(a.y, w.w, ac2[1][3]);
        ac2[2][0] = fmaf(a.z, w.x, ac2[2][0]); ac2[2][1] = fmaf(a.z, w.y, ac2[2][1]);
        ac2[2][2] = fmaf(a.z, w.z, ac2[2][2]); ac2[2][3] = fmaf(a.z, w.w, ac2[2][3]);
        ac2[3][0] = fmaf(a.w, w.x, ac2[3][0]); ac2[3][1] = fmaf(a.w, w.y, ac2[3][1]);
        ac2[3][2] = fmaf(a.w, w.z, ac2[3][2]); ac2[3][3] = fmaf(a.w, w.w, ac2[3][3]);
    }
#pragma unroll
    for (int i = 0; i < 4; ++i) {
        int row = m0 + rr + i;
        if (row >= N) continue;
        ushort4 pk;
        pk.x = f2bf(ac2[i][0]); pk.y = f2bf(ac2[i][1]);
        pk.z = f2bf(ac2[i][2]); pk.w = f2bf(ac2[i][3]);
        *(ushort4*)&ST[(size_t)row * 256 + c0 + cr] = pk;
    }
}

// ---------------------------------------------------------------------------
// Edge scorer: persistent waves, CSR order, 4 edges/wave x 16 lanes x 4 j.
// ST32[n*128 + c]: c<64 src pair (lo=We1,hi=Wl1) for j=c; c>=64 dst pair.
// ---------------------------------------------------------------------------
__global__ __launch_bounds__(256, 6)
void edge_k(const int* __restrict__ off, const int2* __restrict__ csr,
            const float* __restrict__ ef, const uint4* __restrict__ ST128,
            const float* __restrict__ We1, const float* __restrict__ be1,
            const float* __restrict__ We2, const float* __restrict__ be2,
            const float* __restrict__ Wl1, const float* __restrict__ bl1,
            const float* __restrict__ Wl2, const float* __restrict__ bl2,
            float* __restrict__ out, int N, int nwaves) {
    const int l = threadIdx.x & 63;
    const int g = l >> 4, q = l & 15;
    const int j0 = q << 2;
    const int wid = __builtin_amdgcn_readfirstlane(
        blockIdx.x * (blockDim.x >> 6) + (threadIdx.x >> 6));
    // loop-invariant per-lane weights (float4 over j0..j0+3)
    float4 wet[5], wlt[5];
#pragma unroll
    for (int k = 0; k < 5; ++k) {
        wet[k] = *(const float4*)&We1[(128 + k) * 64 + j0];
        wlt[k] = *(const float4*)&Wl1[(128 + k) * 64 + j0];
    }
    const float4 vbe1 = *(const float4*)&be1[j0];
    const float4 vwe2 = *(const float4*)&We2[j0];
    const float4 vbl1 = *(const float4*)&bl1[j0];
    const float4 vwl2 = *(const float4*)&Wl2[j0];
    const float vbe2 = be2[0], vbl2 = bl2[0];

    for (int n = wid; n < N; n += nwaves) {
        int s0 = off[n], s1 = off[n + 1];
        if (s0 >= s1) continue;
        // dst part (ST row n, cols 64+j0..): uint4 = 4 packed pairs
        uint4 dw = ST128[(size_t)n * 32 + 16 + q];
        float4 tb = {bflo(dw.x) + vbe1.x, bflo(dw.y) + vbe1.y,
                     bflo(dw.z) + vbe1.z, bflo(dw.w) + vbe1.w};
        float4 ub = {bfhi(dw.x), bfhi(dw.y), bfhi(dw.z), bfhi(dw.w)};
        for (int i = s0; i < s1; i += 4) {
            int slot = i + g;
            bool act = slot < s1;
            int2 se = csr[act ? slot : s0];
            uint4 sw = ST128[(size_t)se.x * 32 + q];
            float4 t4 = {bflo(sw.x) + tb.x, bflo(sw.y) + tb.y,
                         bflo(sw.z) + tb.z, bflo(sw.w) + tb.w};
            float4 u4 = {bfhi(sw.x) + ub.x, bfhi(sw.y) + ub.y,
                         bfhi(sw.z) + ub.z, bfhi(sw.w) + ub.w};
            const float* ep = ef + (size_t)se.y * 5;
#pragma unroll
            for (int k = 0; k < 5; ++k) {
                float ek = ep[k];
                t4.x = fmaf(ek, wet[k].x, t4.x); t4.y = fmaf(ek, wet[k].y, t4.y);
                t4.z = fmaf(ek, wet[k].z, t4.z); t4.w = fmaf(ek, wet[k].w, t4.w);
                u4.x = fmaf(ek, wlt[k].x, u4.x); u4.y = fmaf(ek, wlt[k].y, u4.y);
                u4.z = fmaf(ek, wlt[k].z, u4.z); u4.w = fmaf(ek, wlt[k].w, u4.w);
            }
            float zs = fast_tanh(t4.x) * vwe2.x + fast_tanh(t4.y) * vwe2.y
                     + fast_tanh(t4.z) * vwe2.z + fast_tanh(t4.w) * vwe2.w;
#pragma unroll
            for (int m = 1; m < 16; m <<= 1) zs += __shfl_xor(zs, m);
            float w = fast_sigmoid(zs + vbe2);
            float os = fmaxf(fmaf(w, u4.x, vbl1.x), 0.f) * vwl2.x
                     + fmaxf(fmaf(w, u4.y, vbl1.y), 0.f) * vwl2.y
                     + fmaxf(fmaf(w, u4.z, vbl1.z), 0.f) * vwl2.z
                     + fmaxf(fmaf(w, u4.w, vbl1.w), 0.f) * vwl2.w;
#pragma unroll
            for (int m = 1; m < 16; m <<= 1) os += __shfl_xor(os, m);
            if (q == 0 && act) out[se.y] = os + vbl2;
        }
    }
}

extern "C" void kernel_launch(void* const* d_in, const int* in_sizes, int n_in,
                              void* d_out, int out_size, void* d_ws, size_t ws_size,
                              hipStream_t stream) {
    const float* nf  = (const float*)d_in[0];
    const float* ef  = (const float*)d_in[1];
    const int*   src = (const int*)d_in[2];
    const int*   dst = (const int*)d_in[3];
    const float* W1s = (const float*)d_in[4];
    const float* W1n = (const float*)d_in[5];
    const float* b1  = (const float*)d_in[6];
    const float* W2s = (const float*)d_in[7];
    const float* W2n = (const float*)d_in[8];
    const float* b2  = (const float*)d_in[9];
    const float* Wnp = (const float*)d_in[10];
    const float* bnp = (const float*)d_in[11];
    const float* We1 = (const float*)d_in[12];
    const float* be1 = (const float*)d_in[13];
    const float* We2 = (const float*)d_in[14];
    const float* be2 = (const float*)d_in[15];
    const float* Wl1 = (const float*)d_in[16];
    const float* bl1 = (const float*)d_in[17];
    const float* Wl2 = (const float*)d_in[18];
    const float* bl2 = (const float*)d_in[19];

    const int N = in_sizes[0] / 4;
    const int E = in_sizes[2];

    // ws layout (float units), peak ~260N = 104 MB (proven budget 128.4 MB):
    //  ST(bf16): [0, 128N)   written by stgemm, read by edge_k
    //    h1:     [0, 64N)    fp32, dead before stgemm
    //    aggh1:  [64N, 128N) dead before stgemm
    //  h2:       [128N, 192N)  (aggnf overlays head early)
    //  ints:     [192N, 228N): csr int2[E] | deg N | off N+1 | cur N | bsum 512
    //  h1b:      [228N, 260N)  bf16-packed h1 (uint[32N])
    //  Wbig:     [260N, 260N + 16384)
    float* wsf = (float*)d_ws;
    unsigned short* ST = (unsigned short*)wsf;
    float* h1    = wsf;
    float* aggh1 = wsf + (size_t)64 * N;
    float* h2    = wsf + (size_t)128 * N;
    float* aggnf = h2;
    int*  ip     = (int*)(wsf + (size_t)192 * N);
    int2* csr    = (int2*)ip;                  // 2E ints
    int*  deg    = ip + 2 * (size_t)E;
    int*  off    = deg + N;
    int*  cur    = off + N + 1;
    int*  bsum   = cur + N;
    unsigned* h1b = (unsigned*)(wsf + (size_t)228 * N);
    float* Wbig  = wsf + (size_t)260 * N;
    float* out   = (float*)d_out;

    const int nblkN1 = (N + 255) / 256;
    const int nblkE  = (E + 255) / 256;
    const int nblkH1 = (N * 32 + 255) / 256;
    const int nblkNw = (N + 3) / 4;
    const int gemmx  = (N + 63) / 64;
    const int EDGE_BLOCKS = 2048;
    const int nwaves = EDGE_BLOCKS * 4;

    // CSR build (packed (src,eid))
    zero_int_k<<<nblkN1, 256, 0, stream>>>(deg, N);
    count_deg_k<<<nblkE, 256, 0, stream>>>(dst, deg, E);
    scan1_k<<<nblkN1, 256, 0, stream>>>(deg, off, bsum, N);
    scan2_k<<<1, 512, 0, stream>>>(bsum, nblkN1);
    scan3_k<<<nblkN1, 256, 0, stream>>>(off, bsum, cur, N, E);
    fill_csr_k<<<nblkE, 256, 0, stream>>>(src, dst, cur, csr, E);

    // layer 1
    aggnf_k<<<nblkN1, 256, 0, stream>>>(off, csr, nf, aggnf, N);
    h1_k<<<nblkH1, 256, 0, stream>>>(nf, aggnf, W1s, W1n, b1, h1, h1b, N);

    // layer 2
    gatherh1_k<<<nblkNw, 256, 0, stream>>>(off, csr, h1b, aggh1, N);
    gemm2_k<<<gemmx, 256, 0, stream>>>(h1, aggh1, W2s, W2n, b2, h2, N);

    // fused per-node MLP + bf16 ST table
    pack_k<<<64, 256, 0, stream>>>(We1, Wl1, Wbig);
    stgemm_k<<<dim3(gemmx, 4), 256, 0, stream>>>(h2, Wnp, bnp, Wbig, ST, N);

    // per-edge scoring
    edge_k<<<EDGE_BLOCKS, 256, 0, stream>>>(off, csr, ef, (const uint4*)ST,
                                            We1, be1, We2, be2, Wl1, bl1, Wl2, bl2,
                                            out, N, nwaves);
}

// Round 6
// 706.182 us; speedup vs baseline: 1.1420x; 1.1420x over previous
//
#include <hip/hip_runtime.h>
#include <math.h>

// ---------------------------------------------------------------------------
// EdgeClassifier: 2x SAGEConv(mean) -> per-node MLP -> edge scorer
//  * layer-1 agg: mean commutes with projection -> aggregate raw nf (4-dim)
//  * h1 kept ONLY as packed bf16 (h1b); layer-2 gather + self-term read it
//  * node_mlp_k: h1/aggh1 -> h2 -> hn -> bf16 ST, all in LDS (one kernel)
//  * edge_k: CSR order, 1 wave/edge-node, wave-uniform csr/ef (scalar loads),
//    2-edge ILP chains; non-persistent grid for occupancy
// ---------------------------------------------------------------------------

__device__ __forceinline__ float fast_tanh(float x) {
    x = fminf(fmaxf(x, -15.f), 15.f);
    float e2 = __expf(2.f * x);
    return (e2 - 1.f) * __builtin_amdgcn_rcpf(e2 + 1.f);
}
__device__ __forceinline__ float fast_sigmoid(float x) {
    x = fminf(fmaxf(x, -60.f), 60.f);
    return __builtin_amdgcn_rcpf(1.f + __expf(-x));
}
__device__ __forceinline__ unsigned short f2bf(float f) {   // RNE
    unsigned u = __float_as_uint(f);
    u = u + 0x7FFFu + ((u >> 16) & 1u);
    return (unsigned short)(u >> 16);
}
__device__ __forceinline__ float bflo(unsigned u) { return __uint_as_float(u << 16); }
__device__ __forceinline__ float bfhi(unsigned u) { return __uint_as_float(u & 0xFFFF0000u); }

__global__ void zero_int_k(int* __restrict__ p, int n) {
    int i = blockIdx.x * blockDim.x + threadIdx.x;
    if (i < n) p[i] = 0;
}

__global__ void count_deg_k(const int* __restrict__ dst, int* __restrict__ deg, int E) {
    int i = blockIdx.x * blockDim.x + threadIdx.x;
    if (i < E) atomicAdd(&deg[dst[i]], 1);
}

__global__ void scan1_k(const int* __restrict__ deg, int* __restrict__ off,
                        int* __restrict__ bsum, int N) {
    __shared__ int tmp[256];
    int i = blockIdx.x * 256 + threadIdx.x;
    int v = (i < N) ? deg[i] : 0;
    tmp[threadIdx.x] = v;
    __syncthreads();
#pragma unroll
    for (int s = 1; s < 256; s <<= 1) {
        int t = (threadIdx.x >= s) ? tmp[threadIdx.x - s] : 0;
        __syncthreads();
        tmp[threadIdx.x] += t;
        __syncthreads();
    }
    if (i < N) off[i] = tmp[threadIdx.x] - v;
    if (threadIdx.x == 255) bsum[blockIdx.x] = tmp[255];
}

__global__ void scan2_k(int* __restrict__ bsum, int nb) {
    __shared__ int tmp[512];
    int i = threadIdx.x;
    int v = (i < nb) ? bsum[i] : 0;
    tmp[i] = v;
    __syncthreads();
#pragma unroll
    for (int s = 1; s < 512; s <<= 1) {
        int t = (i >= s) ? tmp[i - s] : 0;
        __syncthreads();
        tmp[i] += t;
        __syncthreads();
    }
    if (i < nb) bsum[i] = tmp[i] - v;
}

__global__ void scan3_k(int* __restrict__ off, const int* __restrict__ bsum,
                        int* __restrict__ cur, int N, int E) {
    int i = blockIdx.x * 256 + threadIdx.x;
    if (i < N) {
        int v = off[i] + bsum[blockIdx.x];
        off[i] = v;
        cur[i] = v;
    }
    if (i == 0) off[N] = E;
}

__global__ void fill_csr_k(const int* __restrict__ src, const int* __restrict__ dst,
                           int* __restrict__ cur, int2* __restrict__ csr, int E) {
    int e = blockIdx.x * blockDim.x + threadIdx.x;
    if (e >= E) return;
    int pos = atomicAdd(&cur[dst[e]], 1);
    csr[pos] = make_int2(src[e], e);
}

// thread per node: agg_nf[n] = mean of nf[csr.x] (4-dim)
__global__ void aggnf_k(const int* __restrict__ off, const int2* __restrict__ csr,
                        const float* __restrict__ nf, float* __restrict__ agg, int N) {
    int n = blockIdx.x * blockDim.x + threadIdx.x;
    if (n >= N) return;
    int s0 = off[n], s1 = off[n + 1];
    float4 a = {0.f, 0.f, 0.f, 0.f};
    int i = s0;
    for (; i + 4 <= s1; i += 4) {
        float4 r0 = ((const float4*)nf)[csr[i].x];
        float4 r1 = ((const float4*)nf)[csr[i + 1].x];
        float4 r2 = ((const float4*)nf)[csr[i + 2].x];
        float4 r3 = ((const float4*)nf)[csr[i + 3].x];
        a.x += r0.x + r1.x + r2.x + r3.x;
        a.y += r0.y + r1.y + r2.y + r3.y;
        a.z += r0.z + r1.z + r2.z + r3.z;
        a.w += r0.w + r1.w + r2.w + r3.w;
    }
    for (; i < s1; ++i) {
        float4 r = ((const float4*)nf)[csr[i].x];
        a.x += r.x; a.y += r.y; a.z += r.z; a.w += r.w;
    }
    float invd = 1.f / fmaxf((float)(s1 - s0), 1.f);
    a.x *= invd; a.y *= invd; a.z *= invd; a.w *= invd;
    ((float4*)agg)[n] = a;
}

// thread = (n, j-pair): h1 packed bf16 only
__global__ void h1_k(const float* __restrict__ nf, const float* __restrict__ agg,
                     const float* __restrict__ W1s, const float* __restrict__ W1n,
                     const float* __restrict__ b1, unsigned* __restrict__ h1b, int N) {
    int t = blockIdx.x * blockDim.x + threadIdx.x;
    if (t >= N * 32) return;
    int n = t >> 5, j = (t & 31) << 1;
    float4 r = ((const float4*)nf)[n];
    float4 a = ((const float4*)agg)[n];
    float v0 = b1[j]
             + r.x * W1s[j] + r.y * W1s[64 + j] + r.z * W1s[128 + j] + r.w * W1s[192 + j]
             + a.x * W1n[j] + a.y * W1n[64 + j] + a.z * W1n[128 + j] + a.w * W1n[192 + j];
    float v1 = b1[j + 1]
             + r.x * W1s[j + 1] + r.y * W1s[65 + j] + r.z * W1s[129 + j] + r.w * W1s[193 + j]
             + a.x * W1n[j + 1] + a.y * W1n[65 + j] + a.z * W1n[129 + j] + a.w * W1n[193 + j];
    v0 = fmaxf(v0, 0.f);
    v1 = fmaxf(v1, 0.f);
    h1b[t] = ((unsigned)f2bf(v1) << 16) | (unsigned)f2bf(v0);
}

// one wave per node: aggh1[n] = mean of bf16 h1 rows; 4 rows at a time.
__global__ __launch_bounds__(256, 8)
void gatherh1_k(const int* __restrict__ off, const int2* __restrict__ csr,
                const unsigned* __restrict__ h1b, float* __restrict__ aggh1, int N) {
    int n = blockIdx.x * 4 + (threadIdx.x >> 6);
    if (n >= N) return;
    int l = threadIdx.x & 63;
    int g = l >> 4, q = l & 15;
    int s0 = off[n], s1 = off[n + 1];
    float4 acc = {0.f, 0.f, 0.f, 0.f};
    int i = s0;
    for (; i + 4 <= s1; i += 4) {
        int row = csr[i + g].x;
        uint2 v = *(const uint2*)&h1b[(size_t)row * 32 + q * 2];
        acc.x += bflo(v.x); acc.y += bfhi(v.x);
        acc.z += bflo(v.y); acc.w += bfhi(v.y);
    }
    int rem = s1 - i;
    if (g < rem) {
        int row = csr[i + g].x;
        uint2 v = *(const uint2*)&h1b[(size_t)row * 32 + q * 2];
        acc.x += bflo(v.x); acc.y += bfhi(v.x);
        acc.z += bflo(v.y); acc.w += bfhi(v.y);
    }
#pragma unroll
    for (int m = 16; m <= 32; m <<= 1) {
        acc.x += __shfl_xor(acc.x, m);
        acc.y += __shfl_xor(acc.y, m);
        acc.z += __shfl_xor(acc.z, m);
        acc.w += __shfl_xor(acc.w, m);
    }
    if (l < 16) {
        float invd = 1.f / fmaxf((float)(s1 - s0), 1.f);
        acc.x *= invd; acc.y *= invd; acc.z *= invd; acc.w *= invd;
        *(float4*)&aggh1[(size_t)n * 64 + q * 4] = acc;
    }
}

// Wbig col c: halves [0,128)=src-part, [128,256)=dst-part; within a half,
// col 2j -> We1 col j, col 2j+1 -> Wl1 col j (rows 0..63 src, 64..127 dst)
__global__ void pack_k(const float* __restrict__ We1, const float* __restrict__ Wl1,
                       float* __restrict__ Wbig) {
    int t = blockIdx.x * 256 + threadIdx.x;
    if (t >= 64 * 256) return;
    int k = t >> 8, c = t & 255;
    int half = c >> 7, cc = c & 127;
    int j = cc >> 1, p = cc & 1;
    const float* W = p ? Wl1 : We1;
    Wbig[t] = W[(half * 64 + k) * 64 + j];
}

__device__ __forceinline__ void mac64(const float (*hT)[68], const float (*wt)[64],
                                      int rr, int cr, float acc[4][4]) {
#pragma unroll 8
    for (int k = 0; k < 64; ++k) {
        float4 a = *(const float4*)&hT[k][rr];
        float4 w = *(const float4*)&wt[k][cr];
        acc[0][0] = fmaf(a.x, w.x, acc[0][0]); acc[0][1] = fmaf(a.x, w.y, acc[0][1]);
        acc[0][2] = fmaf(a.x, w.z, acc[0][2]); acc[0][3] = fmaf(a.x, w.w, acc[0][3]);
        acc[1][0] = fmaf(a.y, w.x, acc[1][0]); acc[1][1] = fmaf(a.y, w.y, acc[1][1]);
        acc[1][2] = fmaf(a.y, w.z, acc[1][2]); acc[1][3] = fmaf(a.y, w.w, acc[1][3]);
        acc[2][0] = fmaf(a.z, w.x, acc[2][0]); acc[2][1] = fmaf(a.z, w.y, acc[2][1]);
        acc[2][2] = fmaf(a.z, w.z, acc[2][2]); acc[2][3] = fmaf(a.z, w.w, acc[2][3]);
        acc[3][0] = fmaf(a.w, w.x, acc[3][0]); acc[3][1] = fmaf(a.w, w.y, acc[3][1]);
        acc[3][2] = fmaf(a.w, w.z, acc[3][2]); acc[3][3] = fmaf(a.w, w.w, acc[3][3]);
    }
}

// ---------------------------------------------------------------------------
// Fused node MLP: h2 = relu(h1@W2s + aggh1@W2n + b2); hn = relu(h2@Wnp+bnp);
// ST(bf16) = hn @ Wbig (256 cols). All intermediates in LDS.
// ---------------------------------------------------------------------------
__global__ __launch_bounds__(256, 4)
void node_mlp_k(const unsigned* __restrict__ h1b, const float* __restrict__ aggh1,
                const float* __restrict__ W2s, const float* __restrict__ W2n,
                const float* __restrict__ b2, const float* __restrict__ Wnp,
                const float* __restrict__ bnp, const float* __restrict__ Wbig,
                unsigned short* __restrict__ ST, int N) {
    __shared__ __align__(16) float hT[64][68];
    __shared__ __align__(16) float wt[64][64];
    const int t = threadIdx.x;
    const int m0 = blockIdx.x * 64;
    const int cr = (t & 15) << 2, rr = (t >> 4) << 2;
    float acc[4][4] = {};

    // phase A1: self term from bf16 h1
#pragma unroll
    for (int it = 0; it < 8; ++it) {
        int u = it * 256 + t;
        int m = u >> 5, p = u & 31;
        int row = m0 + m;
        unsigned v = (row < N) ? h1b[(size_t)row * 32 + p] : 0u;
        hT[2 * p][m] = bflo(v);
        hT[2 * p + 1][m] = bfhi(v);
    }
#pragma unroll
    for (int it = 0; it < 16; ++it) {
        int k = it * 4 + (t >> 6), c = t & 63;
        wt[k][c] = W2s[k * 64 + c];
    }
    __syncthreads();
    mac64(hT, wt, rr, cr, acc);
    __syncthreads();

    // phase A2: neighbor term (fp32 aggh1)
#pragma unroll
    for (int it = 0; it < 16; ++it) {
        int m = it * 4 + (t >> 6), k = t & 63, row = m0 + m;
        hT[k][m] = (row < N) ? aggh1[(size_t)row * 64 + k] : 0.f;
    }
#pragma unroll
    for (int it = 0; it < 16; ++it) {
        int k = it * 4 + (t >> 6), c = t & 63;
        wt[k][c] = W2n[k * 64 + c];
    }
    __syncthreads();
    mac64(hT, wt, rr, cr, acc);
    __syncthreads();

    // h2 -> hT (transposed), wt <- Wnp
#pragma unroll
    for (int i = 0; i < 4; ++i)
#pragma unroll
        for (int q = 0; q < 4; ++q)
            hT[cr + q][rr + i] = fmaxf(acc[i][q] + b2[cr + q], 0.f);
#pragma unroll
    for (int it = 0; it < 16; ++it) {
        int k = it * 4 + (t >> 6), c = t & 63;
        wt[k][c] = Wnp[k * 64 + c];
    }
    __syncthreads();
    float ac2[4][4] = {};
    mac64(hT, wt, rr, cr, ac2);
    __syncthreads();

    // hn -> hT (transposed)
#pragma unroll
    for (int i = 0; i < 4; ++i)
#pragma unroll
        for (int q = 0; q < 4; ++q)
            hT[cr + q][rr + i] = fmaxf(ac2[i][q] + bnp[cr + q], 0.f);
    __syncthreads();

    // 4 column phases of ST = hn @ Wbig
    for (int cb = 0; cb < 4; ++cb) {
        if (cb) __syncthreads();   // previous mac64 done reading wt
#pragma unroll
        for (int it = 0; it < 16; ++it) {
            int k = it * 4 + (t >> 6), c = t & 63;
            wt[k][c] = Wbig[(size_t)k * 256 + cb * 64 + c];
        }
        __syncthreads();
        float ac3[4][4] = {};
        mac64(hT, wt, rr, cr, ac3);
#pragma unroll
        for (int i = 0; i < 4; ++i) {
            int row = m0 + rr + i;
            if (row >= N) continue;
            ushort4 pk;
            pk.x = f2bf(ac3[i][0]); pk.y = f2bf(ac3[i][1]);
            pk.z = f2bf(ac3[i][2]); pk.w = f2bf(ac3[i][3]);
            *(ushort4*)&ST[(size_t)row * 256 + cb * 64 + cr] = pk;
        }
    }
}

// ---------------------------------------------------------------------------
// Edge scorer: one wave per node, CSR order, 2-edge ILP chains.
// ST32[n*128 + c]: c<64 src pair (lo=We1,hi=Wl1) for j=c; c>=64 dst pair.
// ---------------------------------------------------------------------------
__global__ __launch_bounds__(256, 8)
void edge_k(const int* __restrict__ off, const int2* __restrict__ csr,
            const float* __restrict__ ef, const unsigned* __restrict__ ST32,
            const float* __restrict__ We1, const float* __restrict__ be1,
            const float* __restrict__ We2, const float* __restrict__ be2,
            const float* __restrict__ Wl1, const float* __restrict__ bl1,
            const float* __restrict__ Wl2, const float* __restrict__ bl2,
            float* __restrict__ out, int N) {
    int n = blockIdx.x * 4 + (threadIdx.x >> 6);
    if (n >= N) return;
    const int j = threadIdx.x & 63;
    int s0 = off[n], s1 = off[n + 1];
    if (s0 >= s1) return;

    float wet[5], wlt[5];
#pragma unroll
    for (int k = 0; k < 5; ++k) {
        wet[k] = We1[(128 + k) * 64 + j];
        wlt[k] = Wl1[(128 + k) * 64 + j];
    }
    const float vbe1 = be1[j], vwe2 = We2[j], vbl1 = bl1[j], vwl2 = Wl2[j];
    const float vbe2 = be2[0], vbl2 = bl2[0];

    unsigned pw = ST32[(size_t)n * 128 + 64 + j];
    const float tb = bflo(pw) + vbe1;
    const float ub = bfhi(pw);

    int i = s0;
    for (; i + 2 <= s1; i += 2) {
        int2 ea = csr[i], eb = csr[i + 1];           // wave-uniform
        unsigned swa = ST32[(size_t)ea.x * 128 + j];
        unsigned swb = ST32[(size_t)eb.x * 128 + j];
        float t1a = bflo(swa) + tb, ua = bfhi(swa) + ub;
        float t1b = bflo(swb) + tb, uB = bfhi(swb) + ub;
        const float* epa = ef + (size_t)ea.y * 5;    // wave-uniform -> scalar
        const float* epb = ef + (size_t)eb.y * 5;
#pragma unroll
        for (int k = 0; k < 5; ++k) {
            float eka = epa[k], ekb = epb[k];
            t1a = fmaf(eka, wet[k], t1a); ua = fmaf(eka, wlt[k], ua);
            t1b = fmaf(ekb, wet[k], t1b); uB = fmaf(ekb, wlt[k], uB);
        }
        float za = fast_tanh(t1a) * vwe2;
        float zb = fast_tanh(t1b) * vwe2;
#pragma unroll
        for (int m = 1; m < 64; m <<= 1) {
            za += __shfl_xor(za, m);
            zb += __shfl_xor(zb, m);
        }
        float wa = fast_sigmoid(za + vbe2);
        float wb = fast_sigmoid(zb + vbe2);
        float oa = fmaxf(fmaf(wa, ua, vbl1), 0.f) * vwl2;
        float ob = fmaxf(fmaf(wb, uB, vbl1), 0.f) * vwl2;
#pragma unroll
        for (int m = 1; m < 64; m <<= 1) {
            oa += __shfl_xor(oa, m);
            ob += __shfl_xor(ob, m);
        }
        if (j == 0) {
            out[ea.y] = oa + vbl2;
            out[eb.y] = ob + vbl2;
        }
    }
    if (i < s1) {
        int2 ea = csr[i];
        unsigned swa = ST32[(size_t)ea.x * 128 + j];
        float t1a = bflo(swa) + tb, ua = bfhi(swa) + ub;
        const float* epa = ef + (size_t)ea.y * 5;
#pragma unroll
        for (int k = 0; k < 5; ++k) {
            float eka = epa[k];
            t1a = fmaf(eka, wet[k], t1a);
            ua = fmaf(eka, wlt[k], ua);
        }
        float za = fast_tanh(t1a) * vwe2;
#pragma unroll
        for (int m = 1; m < 64; m <<= 1) za += __shfl_xor(za, m);
        float wa = fast_sigmoid(za + vbe2);
        float oa = fmaxf(fmaf(wa, ua, vbl1), 0.f) * vwl2;
#pragma unroll
        for (int m = 1; m < 64; m <<= 1) oa += __shfl_xor(oa, m);
        if (j == 0) out[ea.y] = oa + vbl2;
    }
}

extern "C" void kernel_launch(void* const* d_in, const int* in_sizes, int n_in,
                              void* d_out, int out_size, void* d_ws, size_t ws_size,
                              hipStream_t stream) {
    const float* nf  = (const float*)d_in[0];
    const float* ef  = (const float*)d_in[1];
    const int*   src = (const int*)d_in[2];
    const int*   dst = (const int*)d_in[3];
    const float* W1s = (const float*)d_in[4];
    const float* W1n = (const float*)d_in[5];
    const float* b1  = (const float*)d_in[6];
    const float* W2s = (const float*)d_in[7];
    const float* W2n = (const float*)d_in[8];
    const float* b2  = (const float*)d_in[9];
    const float* Wnp = (const float*)d_in[10];
    const float* bnp = (const float*)d_in[11];
    const float* We1 = (const float*)d_in[12];
    const float* be1 = (const float*)d_in[13];
    const float* We2 = (const float*)d_in[14];
    const float* be2 = (const float*)d_in[15];
    const float* Wl1 = (const float*)d_in[16];
    const float* bl1 = (const float*)d_in[17];
    const float* Wl2 = (const float*)d_in[18];
    const float* bl2 = (const float*)d_in[19];

    const int N = in_sizes[0] / 4;
    const int E = in_sizes[2];

    // ws layout (float units), peak ~260N + 16K = ~104 MB:
    //  ST(bf16):  [0, 128N)        written by node_mlp, read by edge_k
    //  aggh1:     [128N, 192N)     (aggnf overlays its head, dead before gatherh1)
    //  h1b:       [192N, 224N)     packed bf16 h1
    //  ints:      [224N, ~259N): csr int2[E] | deg N | off N+1 | cur N | bsum 512
    //  Wbig:      [260N, 260N+16384)
    float* wsf = (float*)d_ws;
    unsigned short* ST = (unsigned short*)wsf;
    float* aggh1 = wsf + (size_t)128 * N;
    float* aggnf = aggh1;
    unsigned* h1b = (unsigned*)(wsf + (size_t)192 * N);
    int*  ip   = (int*)(wsf + (size_t)224 * N);
    int2* csr  = (int2*)ip;
    int*  deg  = ip + 2 * (size_t)E;
    int*  off  = deg + N;
    int*  cur  = off + N + 1;
    int*  bsum = cur + N;
    float* Wbig = wsf + (size_t)260 * N;
    float* out  = (float*)d_out;

    const int nblkN1 = (N + 255) / 256;
    const int nblkE  = (E + 255) / 256;
    const int nblkH1 = (N * 32 + 255) / 256;
    const int nblkNw = (N + 3) / 4;
    const int gemmx  = (N + 63) / 64;

    // CSR build (packed (src,eid))
    zero_int_k<<<nblkN1, 256, 0, stream>>>(deg, N);
    count_deg_k<<<nblkE, 256, 0, stream>>>(dst, deg, E);
    scan1_k<<<nblkN1, 256, 0, stream>>>(deg, off, bsum, N);
    scan2_k<<<1, 512, 0, stream>>>(bsum, nblkN1);
    scan3_k<<<nblkN1, 256, 0, stream>>>(off, bsum, cur, N, E);
    fill_csr_k<<<nblkE, 256, 0, stream>>>(src, dst, cur, csr, E);

    // layer 1
    aggnf_k<<<nblkN1, 256, 0, stream>>>(off, csr, nf, aggnf, N);
    h1_k<<<nblkH1, 256, 0, stream>>>(nf, aggnf, W1s, W1n, b1, h1b, N);

    // layer 2 gather
    gatherh1_k<<<nblkNw, 256, 0, stream>>>(off, csr, h1b, aggh1, N);

    // fused node MLP -> bf16 ST table
    pack_k<<<64, 256, 0, stream>>>(We1, Wl1, Wbig);
    node_mlp_k<<<gemmx, 256, 0, stream>>>(h1b, aggh1, W2s, W2n, b2,
                                          Wnp, bnp, Wbig, ST, N);

    // per-edge scoring
    edge_k<<<nblkNw, 256, 0, stream>>>(off, csr, ef, (const unsigned*)ST,
                                       We1, be1, We2, be2, Wl1, bl1, Wl2, bl2,
                                       out, N);
}

// Round 7
// 667.033 us; speedup vs baseline: 1.2090x; 1.0587x over previous
//
#include <hip/hip_runtime.h>
#include <math.h>

// ---------------------------------------------------------------------------
// EdgeClassifier: 2x SAGEConv(mean) -> per-node MLP -> edge scorer
//  * layer-1 agg: mean commutes with projection -> aggregate raw nf (4-dim)
//  * h1 kept ONLY as packed bf16 (h1b); layer-2 gather + self-term read it
//  * node_mlp_k: h1/aggh1 -> h2 -> hn -> bf16 ST, all in LDS (one kernel)
//  * edge_k: CSR order, 2 edges/wave x 32 lanes x 2 j/lane; scalar ef via
//    readlane; half-wave shuffle reductions (5 steps, both edges at once)
// ---------------------------------------------------------------------------

__device__ __forceinline__ float fast_tanh(float x) {
    x = fminf(fmaxf(x, -15.f), 15.f);
    float e2 = __expf(2.f * x);
    return (e2 - 1.f) * __builtin_amdgcn_rcpf(e2 + 1.f);
}
__device__ __forceinline__ float fast_sigmoid(float x) {
    x = fminf(fmaxf(x, -60.f), 60.f);
    return __builtin_amdgcn_rcpf(1.f + __expf(-x));
}
__device__ __forceinline__ unsigned short f2bf(float f) {   // RNE
    unsigned u = __float_as_uint(f);
    u = u + 0x7FFFu + ((u >> 16) & 1u);
    return (unsigned short)(u >> 16);
}
__device__ __forceinline__ float bflo(unsigned u) { return __uint_as_float(u << 16); }
__device__ __forceinline__ float bfhi(unsigned u) { return __uint_as_float(u & 0xFFFF0000u); }

__global__ void zero_int_k(int* __restrict__ p, int n) {
    int i = blockIdx.x * blockDim.x + threadIdx.x;
    if (i < n) p[i] = 0;
}

__global__ void count_deg_k(const int* __restrict__ dst, int* __restrict__ deg, int E) {
    int i = blockIdx.x * blockDim.x + threadIdx.x;
    if (i < E) atomicAdd(&deg[dst[i]], 1);
}

__global__ void scan1_k(const int* __restrict__ deg, int* __restrict__ off,
                        int* __restrict__ bsum, int N) {
    __shared__ int tmp[256];
    int i = blockIdx.x * 256 + threadIdx.x;
    int v = (i < N) ? deg[i] : 0;
    tmp[threadIdx.x] = v;
    __syncthreads();
#pragma unroll
    for (int s = 1; s < 256; s <<= 1) {
        int t = (threadIdx.x >= s) ? tmp[threadIdx.x - s] : 0;
        __syncthreads();
        tmp[threadIdx.x] += t;
        __syncthreads();
    }
    if (i < N) off[i] = tmp[threadIdx.x] - v;
    if (threadIdx.x == 255) bsum[blockIdx.x] = tmp[255];
}

__global__ void scan2_k(int* __restrict__ bsum, int nb) {
    __shared__ int tmp[512];
    int i = threadIdx.x;
    int v = (i < nb) ? bsum[i] : 0;
    tmp[i] = v;
    __syncthreads();
#pragma unroll
    for (int s = 1; s < 512; s <<= 1) {
        int t = (i >= s) ? tmp[i - s] : 0;
        __syncthreads();
        tmp[i] += t;
        __syncthreads();
    }
    if (i < nb) bsum[i] = tmp[i] - v;
}

__global__ void scan3_k(int* __restrict__ off, const int* __restrict__ bsum,
                        int* __restrict__ cur, int N, int E) {
    int i = blockIdx.x * 256 + threadIdx.x;
    if (i < N) {
        int v = off[i] + bsum[blockIdx.x];
        off[i] = v;
        cur[i] = v;
    }
    if (i == 0) off[N] = E;
}

__global__ void fill_csr_k(const int* __restrict__ src, const int* __restrict__ dst,
                           int* __restrict__ cur, int2* __restrict__ csr, int E) {
    int e = blockIdx.x * blockDim.x + threadIdx.x;
    if (e >= E) return;
    int pos = atomicAdd(&cur[dst[e]], 1);
    csr[pos] = make_int2(src[e], e);
}

// thread per node: agg_nf[n] = mean of nf[csr.x] (4-dim)
__global__ void aggnf_k(const int* __restrict__ off, const int2* __restrict__ csr,
                        const float* __restrict__ nf, float* __restrict__ agg, int N) {
    int n = blockIdx.x * blockDim.x + threadIdx.x;
    if (n >= N) return;
    int s0 = off[n], s1 = off[n + 1];
    float4 a = {0.f, 0.f, 0.f, 0.f};
    int i = s0;
    for (; i + 4 <= s1; i += 4) {
        float4 r0 = ((const float4*)nf)[csr[i].x];
        float4 r1 = ((const float4*)nf)[csr[i + 1].x];
        float4 r2 = ((const float4*)nf)[csr[i + 2].x];
        float4 r3 = ((const float4*)nf)[csr[i + 3].x];
        a.x += r0.x + r1.x + r2.x + r3.x;
        a.y += r0.y + r1.y + r2.y + r3.y;
        a.z += r0.z + r1.z + r2.z + r3.z;
        a.w += r0.w + r1.w + r2.w + r3.w;
    }
    for (; i < s1; ++i) {
        float4 r = ((const float4*)nf)[csr[i].x];
        a.x += r.x; a.y += r.y; a.z += r.z; a.w += r.w;
    }
    float invd = 1.f / fmaxf((float)(s1 - s0), 1.f);
    a.x *= invd; a.y *= invd; a.z *= invd; a.w *= invd;
    ((float4*)agg)[n] = a;
}

// thread = (n, j-pair): h1 packed bf16 only
__global__ void h1_k(const float* __restrict__ nf, const float* __restrict__ agg,
                     const float* __restrict__ W1s, const float* __restrict__ W1n,
                     const float* __restrict__ b1, unsigned* __restrict__ h1b, int N) {
    int t = blockIdx.x * blockDim.x + threadIdx.x;
    if (t >= N * 32) return;
    int n = t >> 5, j = (t & 31) << 1;
    float4 r = ((const float4*)nf)[n];
    float4 a = ((const float4*)agg)[n];
    float v0 = b1[j]
             + r.x * W1s[j] + r.y * W1s[64 + j] + r.z * W1s[128 + j] + r.w * W1s[192 + j]
             + a.x * W1n[j] + a.y * W1n[64 + j] + a.z * W1n[128 + j] + a.w * W1n[192 + j];
    float v1 = b1[j + 1]
             + r.x * W1s[j + 1] + r.y * W1s[65 + j] + r.z * W1s[129 + j] + r.w * W1s[193 + j]
             + a.x * W1n[j + 1] + a.y * W1n[65 + j] + a.z * W1n[129 + j] + a.w * W1n[193 + j];
    v0 = fmaxf(v0, 0.f);
    v1 = fmaxf(v1, 0.f);
    h1b[t] = ((unsigned)f2bf(v1) << 16) | (unsigned)f2bf(v0);
}

// one wave per node: aggh1[n] = mean of bf16 h1 rows; 4 rows at a time.
__global__ __launch_bounds__(256, 8)
void gatherh1_k(const int* __restrict__ off, const int2* __restrict__ csr,
                const unsigned* __restrict__ h1b, float* __restrict__ aggh1, int N) {
    int n = blockIdx.x * 4 + (threadIdx.x >> 6);
    if (n >= N) return;
    int l = threadIdx.x & 63;
    int g = l >> 4, q = l & 15;
    int s0 = off[n], s1 = off[n + 1];
    float4 acc = {0.f, 0.f, 0.f, 0.f};
    int i = s0;
    for (; i + 4 <= s1; i += 4) {
        int row = csr[i + g].x;
        uint2 v = *(const uint2*)&h1b[(size_t)row * 32 + q * 2];
        acc.x += bflo(v.x); acc.y += bfhi(v.x);
        acc.z += bflo(v.y); acc.w += bfhi(v.y);
    }
    int rem = s1 - i;
    if (g < rem) {
        int row = csr[i + g].x;
        uint2 v = *(const uint2*)&h1b[(size_t)row * 32 + q * 2];
        acc.x += bflo(v.x); acc.y += bfhi(v.x);
        acc.z += bflo(v.y); acc.w += bfhi(v.y);
    }
#pragma unroll
    for (int m = 16; m <= 32; m <<= 1) {
        acc.x += __shfl_xor(acc.x, m);
        acc.y += __shfl_xor(acc.y, m);
        acc.z += __shfl_xor(acc.z, m);
        acc.w += __shfl_xor(acc.w, m);
    }
    if (l < 16) {
        float invd = 1.f / fmaxf((float)(s1 - s0), 1.f);
        acc.x *= invd; acc.y *= invd; acc.z *= invd; acc.w *= invd;
        *(float4*)&aggh1[(size_t)n * 64 + q * 4] = acc;
    }
}

// Wbig col c: halves [0,128)=src-part, [128,256)=dst-part; within a half,
// col 2j -> We1 col j, col 2j+1 -> Wl1 col j (rows 0..63 src, 64..127 dst)
__global__ void pack_k(const float* __restrict__ We1, const float* __restrict__ Wl1,
                       float* __restrict__ Wbig) {
    int t = blockIdx.x * 256 + threadIdx.x;
    if (t >= 64 * 256) return;
    int k = t >> 8, c = t & 255;
    int half = c >> 7, cc = c & 127;
    int j = cc >> 1, p = cc & 1;
    const float* W = p ? Wl1 : We1;
    Wbig[t] = W[(half * 64 + k) * 64 + j];
}

__device__ __forceinline__ void mac64(const float (*hT)[68], const float (*wt)[64],
                                      int rr, int cr, float acc[4][4]) {
#pragma unroll 8
    for (int k = 0; k < 64; ++k) {
        float4 a = *(const float4*)&hT[k][rr];
        float4 w = *(const float4*)&wt[k][cr];
        acc[0][0] = fmaf(a.x, w.x, acc[0][0]); acc[0][1] = fmaf(a.x, w.y, acc[0][1]);
        acc[0][2] = fmaf(a.x, w.z, acc[0][2]); acc[0][3] = fmaf(a.x, w.w, acc[0][3]);
        acc[1][0] = fmaf(a.y, w.x, acc[1][0]); acc[1][1] = fmaf(a.y, w.y, acc[1][1]);
        acc[1][2] = fmaf(a.y, w.z, acc[1][2]); acc[1][3] = fmaf(a.y, w.w, acc[1][3]);
        acc[2][0] = fmaf(a.z, w.x, acc[2][0]); acc[2][1] = fmaf(a.z, w.y, acc[2][1]);
        acc[2][2] = fmaf(a.z, w.z, acc[2][2]); acc[2][3] = fmaf(a.z, w.w, acc[2][3]);
        acc[3][0] = fmaf(a.w, w.x, acc[3][0]); acc[3][1] = fmaf(a.w, w.y, acc[3][1]);
        acc[3][2] = fmaf(a.w, w.z, acc[3][2]); acc[3][3] = fmaf(a.w, w.w, acc[3][3]);
    }
}

// ---------------------------------------------------------------------------
// Fused node MLP: h2 = relu(h1@W2s + aggh1@W2n + b2); hn = relu(h2@Wnp+bnp);
// ST(bf16) = hn @ Wbig (256 cols). All intermediates in LDS.
// ---------------------------------------------------------------------------
__global__ __launch_bounds__(256, 4)
void node_mlp_k(const unsigned* __restrict__ h1b, const float* __restrict__ aggh1,
                const float* __restrict__ W2s, const float* __restrict__ W2n,
                const float* __restrict__ b2, const float* __restrict__ Wnp,
                const float* __restrict__ bnp, const float* __restrict__ Wbig,
                unsigned short* __restrict__ ST, int N) {
    __shared__ __align__(16) float hT[64][68];
    __shared__ __align__(16) float wt[64][64];
    const int t = threadIdx.x;
    const int m0 = blockIdx.x * 64;
    const int cr = (t & 15) << 2, rr = (t >> 4) << 2;
    float acc[4][4] = {};

    // phase A1: self term from bf16 h1
#pragma unroll
    for (int it = 0; it < 8; ++it) {
        int u = it * 256 + t;
        int m = u >> 5, p = u & 31;
        int row = m0 + m;
        unsigned v = (row < N) ? h1b[(size_t)row * 32 + p] : 0u;
        hT[2 * p][m] = bflo(v);
        hT[2 * p + 1][m] = bfhi(v);
    }
#pragma unroll
    for (int it = 0; it < 16; ++it) {
        int k = it * 4 + (t >> 6), c = t & 63;
        wt[k][c] = W2s[k * 64 + c];
    }
    __syncthreads();
    mac64(hT, wt, rr, cr, acc);
    __syncthreads();

    // phase A2: neighbor term (fp32 aggh1)
#pragma unroll
    for (int it = 0; it < 16; ++it) {
        int m = it * 4 + (t >> 6), k = t & 63, row = m0 + m;
        hT[k][m] = (row < N) ? aggh1[(size_t)row * 64 + k] : 0.f;
    }
#pragma unroll
    for (int it = 0; it < 16; ++it) {
        int k = it * 4 + (t >> 6), c = t & 63;
        wt[k][c] = W2n[k * 64 + c];
    }
    __syncthreads();
    mac64(hT, wt, rr, cr, acc);
    __syncthreads();

    // h2 -> hT (transposed), wt <- Wnp
#pragma unroll
    for (int i = 0; i < 4; ++i)
#pragma unroll
        for (int q = 0; q < 4; ++q)
            hT[cr + q][rr + i] = fmaxf(acc[i][q] + b2[cr + q], 0.f);
#pragma unroll
    for (int it = 0; it < 16; ++it) {
        int k = it * 4 + (t >> 6), c = t & 63;
        wt[k][c] = Wnp[k * 64 + c];
    }
    __syncthreads();
    float ac2[4][4] = {};
    mac64(hT, wt, rr, cr, ac2);
    __syncthreads();

    // hn -> hT (transposed)
#pragma unroll
    for (int i = 0; i < 4; ++i)
#pragma unroll
        for (int q = 0; q < 4; ++q)
            hT[cr + q][rr + i] = fmaxf(ac2[i][q] + bnp[cr + q], 0.f);
    __syncthreads();

    // 4 column phases of ST = hn @ Wbig
    for (int cb = 0; cb < 4; ++cb) {
        if (cb) __syncthreads();   // previous mac64 done reading wt
#pragma unroll
        for (int it = 0; it < 16; ++it) {
            int k = it * 4 + (t >> 6), c = t & 63;
            wt[k][c] = Wbig[(size_t)k * 256 + cb * 64 + c];
        }
        __syncthreads();
        float ac3[4][4] = {};
        mac64(hT, wt, rr, cr, ac3);
#pragma unroll
        for (int i = 0; i < 4; ++i) {
            int row = m0 + rr + i;
            if (row >= N) continue;
            ushort4 pk;
            pk.x = f2bf(ac3[i][0]); pk.y = f2bf(ac3[i][1]);
            pk.z = f2bf(ac3[i][2]); pk.w = f2bf(ac3[i][3]);
            *(ushort4*)&ST[(size_t)row * 256 + cb * 64 + cr] = pk;
        }
    }
}

// ---------------------------------------------------------------------------
// Edge scorer: one wave per node, CSR order, 2 edges/wave x 32 lanes x 2 j.
// ST32[n*128 + c]: c<64 src pair (lo=We1,hi=Wl1) for j=c; c>=64 dst pair.
// Lanes 0..31 = edge A, 32..63 = edge B; lane q covers j=2q,2q+1 (uint2).
// ef rows read via readlane -> scalar loads; reductions are 5-step
// half-wave trees serving both edges at once.
// ---------------------------------------------------------------------------
__global__ __launch_bounds__(256, 8)
void edge_k(const int* __restrict__ off, const int2* __restrict__ csr,
            const float* __restrict__ ef, const unsigned* __restrict__ ST32,
            const float* __restrict__ We1, const float* __restrict__ be1,
            const float* __restrict__ We2, const float* __restrict__ be2,
            const float* __restrict__ Wl1, const float* __restrict__ bl1,
            const float* __restrict__ Wl2, const float* __restrict__ bl2,
            float* __restrict__ out, int N) {
    int n = blockIdx.x * 4 + (threadIdx.x >> 6);
    if (n >= N) return;
    const int l = threadIdx.x & 63;
    const int half = l >> 5;          // 0: edge A, 1: edge B
    const int q = l & 31;             // j-pair: j0=2q, j1=2q+1
    const int j0 = q << 1;
    int s0 = off[n], s1 = off[n + 1];
    if (s0 >= s1) return;

    float2 wet[5], wlt[5];
#pragma unroll
    for (int k = 0; k < 5; ++k) {
        wet[k] = *(const float2*)&We1[(128 + k) * 64 + j0];
        wlt[k] = *(const float2*)&Wl1[(128 + k) * 64 + j0];
    }
    const float2 vbe1 = *(const float2*)&be1[j0];
    const float2 vwe2 = *(const float2*)&We2[j0];
    const float2 vbl1 = *(const float2*)&bl1[j0];
    const float2 vwl2 = *(const float2*)&Wl2[j0];
    const float vbe2 = be2[0], vbl2 = bl2[0];

    // dst part (per-node, loaded once)
    uint2 pw = *(const uint2*)&ST32[(size_t)n * 128 + 64 + j0];
    const float tbx = bflo(pw.x) + vbe1.x, tby = bflo(pw.y) + vbe1.y;
    const float ubx = bfhi(pw.x), uby = bfhi(pw.y);

    for (int i = s0; i < s1; i += 2) {
        int ii = i + half;
        bool act = ii < s1;
        int2 se = csr[act ? ii : s0];                 // half-uniform
        uint2 sw = *(const uint2*)&ST32[(size_t)se.x * 128 + j0];
        float t1x = bflo(sw.x) + tbx, t1y = bflo(sw.y) + tby;
        float ux  = bfhi(sw.x) + ubx, uy  = bfhi(sw.y) + uby;
        // scalar ef rows for both edges
        int eidA = __builtin_amdgcn_readfirstlane(se.y);
        int eidB = __builtin_amdgcn_readlane(se.y, 32);
        const float* epa = ef + (size_t)eidA * 5;
        const float* epb = ef + (size_t)eidB * 5;
#pragma unroll
        for (int k = 0; k < 5; ++k) {
            float eka = epa[k], ekb = epb[k];         // s_load, wave-uniform
            float ek = half ? ekb : eka;              // 1 cndmask
            t1x = fmaf(ek, wet[k].x, t1x); t1y = fmaf(ek, wet[k].y, t1y);
            ux  = fmaf(ek, wlt[k].x, ux);  uy  = fmaf(ek, wlt[k].y, uy);
        }
        float z = fast_tanh(t1x) * vwe2.x + fast_tanh(t1y) * vwe2.y;
#pragma unroll
        for (int m = 1; m < 32; m <<= 1) z += __shfl_xor(z, m);
        float w = fast_sigmoid(z + vbe2);
        float o = fmaxf(fmaf(w, ux, vbl1.x), 0.f) * vwl2.x
                + fmaxf(fmaf(w, uy, vbl1.y), 0.f) * vwl2.y;
#pragma unroll
        for (int m = 1; m < 32; m <<= 1) o += __shfl_xor(o, m);
        if (q == 0 && act) out[se.y] = o + vbl2;      // lanes 0 and 32
    }
}

extern "C" void kernel_launch(void* const* d_in, const int* in_sizes, int n_in,
                              void* d_out, int out_size, void* d_ws, size_t ws_size,
                              hipStream_t stream) {
    const float* nf  = (const float*)d_in[0];
    const float* ef  = (const float*)d_in[1];
    const int*   src = (const int*)d_in[2];
    const int*   dst = (const int*)d_in[3];
    const float* W1s = (const float*)d_in[4];
    const float* W1n = (const float*)d_in[5];
    const float* b1  = (const float*)d_in[6];
    const float* W2s = (const float*)d_in[7];
    const float* W2n = (const float*)d_in[8];
    const float* b2  = (const float*)d_in[9];
    const float* Wnp = (const float*)d_in[10];
    const float* bnp = (const float*)d_in[11];
    const float* We1 = (const float*)d_in[12];
    const float* be1 = (const float*)d_in[13];
    const float* We2 = (const float*)d_in[14];
    const float* be2 = (const float*)d_in[15];
    const float* Wl1 = (const float*)d_in[16];
    const float* bl1 = (const float*)d_in[17];
    const float* Wl2 = (const float*)d_in[18];
    const float* bl2 = (const float*)d_in[19];

    const int N = in_sizes[0] / 4;
    const int E = in_sizes[2];

    // ws layout (float units), peak ~260N + 16K = ~104 MB:
    //  ST(bf16):  [0, 128N)        written by node_mlp, read by edge_k
    //  aggh1:     [128N, 192N)     (aggnf overlays its head, dead before gatherh1)
    //  h1b:       [192N, 224N)     packed bf16 h1
    //  ints:      [224N, ~259N): csr int2[E] | deg N | off N+1 | cur N | bsum 512
    //  Wbig:      [260N, 260N+16384)
    float* wsf = (float*)d_ws;
    unsigned short* ST = (unsigned short*)wsf;
    float* aggh1 = wsf + (size_t)128 * N;
    float* aggnf = aggh1;
    unsigned* h1b = (unsigned*)(wsf + (size_t)192 * N);
    int*  ip   = (int*)(wsf + (size_t)224 * N);
    int2* csr  = (int2*)ip;
    int*  deg  = ip + 2 * (size_t)E;
    int*  off  = deg + N;
    int*  cur  = off + N + 1;
    int*  bsum = cur + N;
    float* Wbig = wsf + (size_t)260 * N;
    float* out  = (float*)d_out;

    const int nblkN1 = (N + 255) / 256;
    const int nblkE  = (E + 255) / 256;
    const int nblkH1 = (N * 32 + 255) / 256;
    const int nblkNw = (N + 3) / 4;
    const int gemmx  = (N + 63) / 64;

    // CSR build (packed (src,eid))
    zero_int_k<<<nblkN1, 256, 0, stream>>>(deg, N);
    count_deg_k<<<nblkE, 256, 0, stream>>>(dst, deg, E);
    scan1_k<<<nblkN1, 256, 0, stream>>>(deg, off, bsum, N);
    scan2_k<<<1, 512, 0, stream>>>(bsum, nblkN1);
    scan3_k<<<nblkN1, 256, 0, stream>>>(off, bsum, cur, N, E);
    fill_csr_k<<<nblkE, 256, 0, stream>>>(src, dst, cur, csr, E);

    // layer 1
    aggnf_k<<<nblkN1, 256, 0, stream>>>(off, csr, nf, aggnf, N);
    h1_k<<<nblkH1, 256, 0, stream>>>(nf, aggnf, W1s, W1n, b1, h1b, N);

    // layer 2 gather
    gatherh1_k<<<nblkNw, 256, 0, stream>>>(off, csr, h1b, aggh1, N);

    // fused node MLP -> bf16 ST table
    pack_k<<<64, 256, 0, stream>>>(We1, Wl1, Wbig);
    node_mlp_k<<<gemmx, 256, 0, stream>>>(h1b, aggh1, W2s, W2n, b2,
                                          Wnp, bnp, Wbig, ST, N);

    // per-edge scoring
    edge_k<<<nblkNw, 256, 0, stream>>>(off, csr, ef, (const unsigned*)ST,
                                       We1, be1, We2, be2, Wl1, bl1, Wl2, bl2,
                                       out, N);
}

// Round 8
// 548.548 us; speedup vs baseline: 1.4702x; 1.2160x over previous
//
#include <hip/hip_runtime.h>
#include <math.h>

// ---------------------------------------------------------------------------
// EdgeClassifier: 2x SAGEConv(mean) -> per-node MLP -> edge scorer
//  * layer-1 agg: mean commutes with projection -> aggregate raw nf (4-dim),
//    fused with h1 compute in one wave-per-node kernel (aggh1f_k)
//  * h1 kept ONLY as packed bf16 (h1b)
//  * CSR: 1 atomic pass (rank) + scan + atomic-free scatter fill
//  * node_mlp_k: h1/aggh1 -> h2 -> hn -> bf16 ST in LDS; Wbig mapping inline
//  * edge_k: CSR order, 4 edges/wave x 16 lanes x 4 j; DPP 16-lane reductions
//    (no DS); scalar ef via readlane x4
// ---------------------------------------------------------------------------

__device__ __forceinline__ float fast_tanh(float x) {
    x = fminf(fmaxf(x, -15.f), 15.f);
    float e2 = __expf(2.f * x);
    return (e2 - 1.f) * __builtin_amdgcn_rcpf(e2 + 1.f);
}
__device__ __forceinline__ float fast_sigmoid(float x) {
    x = fminf(fmaxf(x, -60.f), 60.f);
    return __builtin_amdgcn_rcpf(1.f + __expf(-x));
}
__device__ __forceinline__ unsigned short f2bf(float f) {   // RNE
    unsigned u = __float_as_uint(f);
    u = u + 0x7FFFu + ((u >> 16) & 1u);
    return (unsigned short)(u >> 16);
}
__device__ __forceinline__ float bflo(unsigned u) { return __uint_as_float(u << 16); }
__device__ __forceinline__ float bfhi(unsigned u) { return __uint_as_float(u & 0xFFFF0000u); }

// 16-lane all-reduce sum, pure DPP (no LDS/DS): quad xor1, xor2, 8-mirror, 16-mirror
__device__ __forceinline__ float dpp_sum16(float x) {
    int t;
    t = __builtin_amdgcn_update_dpp(0, __float_as_int(x), 0xB1, 0xF, 0xF, true);  // quad_perm(1,0,3,2)
    x += __int_as_float(t);
    t = __builtin_amdgcn_update_dpp(0, __float_as_int(x), 0x4E, 0xF, 0xF, true);  // quad_perm(2,3,0,1)
    x += __int_as_float(t);
    t = __builtin_amdgcn_update_dpp(0, __float_as_int(x), 0x141, 0xF, 0xF, true); // row_half_mirror
    x += __int_as_float(t);
    t = __builtin_amdgcn_update_dpp(0, __float_as_int(x), 0x140, 0xF, 0xF, true); // row_mirror
    x += __int_as_float(t);
    return x;
}

// rank[e] = arrival index among edges sharing dst; deg accumulates counts
__global__ void rank_k(const int* __restrict__ dst, int* __restrict__ deg,
                       int* __restrict__ rank, int E) {
    int e = blockIdx.x * blockDim.x + threadIdx.x;
    if (e < E) rank[e] = atomicAdd(&deg[dst[e]], 1);
}

__global__ void scan1_k(const int* __restrict__ deg, int* __restrict__ off,
                        int* __restrict__ bsum, int N) {
    __shared__ int tmp[256];
    int i = blockIdx.x * 256 + threadIdx.x;
    int v = (i < N) ? deg[i] : 0;
    tmp[threadIdx.x] = v;
    __syncthreads();
#pragma unroll
    for (int s = 1; s < 256; s <<= 1) {
        int t = (threadIdx.x >= s) ? tmp[threadIdx.x - s] : 0;
        __syncthreads();
        tmp[threadIdx.x] += t;
        __syncthreads();
    }
    if (i < N) off[i] = tmp[threadIdx.x] - v;
    if (threadIdx.x == 255) bsum[blockIdx.x] = tmp[255];
}

__global__ void scan2_k(int* __restrict__ bsum, int nb) {
    __shared__ int tmp[512];
    int i = threadIdx.x;
    int v = (i < nb) ? bsum[i] : 0;
    tmp[i] = v;
    __syncthreads();
#pragma unroll
    for (int s = 1; s < 512; s <<= 1) {
        int t = (i >= s) ? tmp[i - s] : 0;
        __syncthreads();
        tmp[i] += t;
        __syncthreads();
    }
    if (i < nb) bsum[i] = tmp[i] - v;
}

__global__ void scan3_k(int* __restrict__ off, const int* __restrict__ bsum,
                        int N, int E) {
    int i = blockIdx.x * 256 + threadIdx.x;
    if (i < N) off[i] += bsum[blockIdx.x];
    if (i == 0) off[N] = E;
}

// atomic-free CSR fill using precomputed ranks
__global__ void fill2_k(const int* __restrict__ src, const int* __restrict__ dst,
                        const int* __restrict__ off, const int* __restrict__ rank,
                        int2* __restrict__ csr, int E) {
    int e = blockIdx.x * blockDim.x + threadIdx.x;
    if (e >= E) return;
    csr[off[dst[e]] + rank[e]] = make_int2(src[e], e);
}

// one wave per node: aggnf = mean of nf[neighbors] (butterfly), then
// h1[j] = relu(nf@W1s + aggnf@W1n + b1)[j] per lane, stored as bf16
__global__ __launch_bounds__(256, 8)
void aggh1f_k(const int* __restrict__ off, const int2* __restrict__ csr,
              const float* __restrict__ nf,
              const float* __restrict__ W1s, const float* __restrict__ W1n,
              const float* __restrict__ b1, unsigned short* __restrict__ h1s, int N) {
    int n = blockIdx.x * 4 + (threadIdx.x >> 6);
    if (n >= N) return;
    int l = threadIdx.x & 63;
    int s0 = off[n], s1 = off[n + 1];
    float4 a = {0.f, 0.f, 0.f, 0.f};
    for (int i = s0 + l; i < s1; i += 64) {
        float4 r = ((const float4*)nf)[csr[i].x];
        a.x += r.x; a.y += r.y; a.z += r.z; a.w += r.w;
    }
#pragma unroll
    for (int m = 1; m < 64; m <<= 1) {
        a.x += __shfl_xor(a.x, m);
        a.y += __shfl_xor(a.y, m);
        a.z += __shfl_xor(a.z, m);
        a.w += __shfl_xor(a.w, m);
    }
    float invd = 1.f / fmaxf((float)(s1 - s0), 1.f);
    a.x *= invd; a.y *= invd; a.z *= invd; a.w *= invd;
    float4 r = ((const float4*)nf)[n];
    float v = b1[l]
            + r.x * W1s[l] + r.y * W1s[64 + l] + r.z * W1s[128 + l] + r.w * W1s[192 + l]
            + a.x * W1n[l] + a.y * W1n[64 + l] + a.z * W1n[128 + l] + a.w * W1n[192 + l];
    h1s[(size_t)n * 64 + l] = f2bf(fmaxf(v, 0.f));
}

// one wave per node: aggh1[n] = mean of bf16 h1 rows; 8 rows in flight
__global__ __launch_bounds__(256, 8)
void gatherh1_k(const int* __restrict__ off, const int2* __restrict__ csr,
                const unsigned* __restrict__ h1b, float* __restrict__ aggh1, int N) {
    int n = blockIdx.x * 4 + (threadIdx.x >> 6);
    if (n >= N) return;
    int l = threadIdx.x & 63;
    int g = l >> 4, q = l & 15;
    int s0 = off[n], s1 = off[n + 1];
    float4 acc = {0.f, 0.f, 0.f, 0.f};
    int i = s0;
    for (; i + 8 <= s1; i += 8) {
        int r0 = csr[i + g].x;
        int r1 = csr[i + 4 + g].x;
        uint2 v0 = *(const uint2*)&h1b[(size_t)r0 * 32 + q * 2];
        uint2 v1 = *(const uint2*)&h1b[(size_t)r1 * 32 + q * 2];
        acc.x += bflo(v0.x) + bflo(v1.x);
        acc.y += bfhi(v0.x) + bfhi(v1.x);
        acc.z += bflo(v0.y) + bflo(v1.y);
        acc.w += bfhi(v0.y) + bfhi(v1.y);
    }
    for (; i + 4 <= s1; i += 4) {
        int r0 = csr[i + g].x;
        uint2 v0 = *(const uint2*)&h1b[(size_t)r0 * 32 + q * 2];
        acc.x += bflo(v0.x); acc.y += bfhi(v0.x);
        acc.z += bflo(v0.y); acc.w += bfhi(v0.y);
    }
    int rem = s1 - i;
    if (g < rem) {
        int r0 = csr[i + g].x;
        uint2 v0 = *(const uint2*)&h1b[(size_t)r0 * 32 + q * 2];
        acc.x += bflo(v0.x); acc.y += bfhi(v0.x);
        acc.z += bflo(v0.y); acc.w += bfhi(v0.y);
    }
#pragma unroll
    for (int m = 16; m <= 32; m <<= 1) {
        acc.x += __shfl_xor(acc.x, m);
        acc.y += __shfl_xor(acc.y, m);
        acc.z += __shfl_xor(acc.z, m);
        acc.w += __shfl_xor(acc.w, m);
    }
    if (l < 16) {
        float invd = 1.f / fmaxf((float)(s1 - s0), 1.f);
        acc.x *= invd; acc.y *= invd; acc.z *= invd; acc.w *= invd;
        *(float4*)&aggh1[(size_t)n * 64 + q * 4] = acc;
    }
}

__device__ __forceinline__ void mac64(const float (*hT)[68], const float (*wt)[64],
                                      int rr, int cr, float acc[4][4]) {
#pragma unroll 8
    for (int k = 0; k < 64; ++k) {
        float4 a = *(const float4*)&hT[k][rr];
        float4 w = *(const float4*)&wt[k][cr];
        acc[0][0] = fmaf(a.x, w.x, acc[0][0]); acc[0][1] = fmaf(a.x, w.y, acc[0][1]);
        acc[0][2] = fmaf(a.x, w.z, acc[0][2]); acc[0][3] = fmaf(a.x, w.w, acc[0][3]);
        acc[1][0] = fmaf(a.y, w.x, acc[1][0]); acc[1][1] = fmaf(a.y, w.y, acc[1][1]);
        acc[1][2] = fmaf(a.y, w.z, acc[1][2]); acc[1][3] = fmaf(a.y, w.w, acc[1][3]);
        acc[2][0] = fmaf(a.z, w.x, acc[2][0]); acc[2][1] = fmaf(a.z, w.y, acc[2][1]);
        acc[2][2] = fmaf(a.z, w.z, acc[2][2]); acc[2][3] = fmaf(a.z, w.w, acc[2][3]);
        acc[3][0] = fmaf(a.w, w.x, acc[3][0]); acc[3][1] = fmaf(a.w, w.y, acc[3][1]);
        acc[3][2] = fmaf(a.w, w.z, acc[3][2]); acc[3][3] = fmaf(a.w, w.w, acc[3][3]);
    }
}

// ---------------------------------------------------------------------------
// Fused node MLP: h2 = relu(h1@W2s + aggh1@W2n + b2); hn = relu(h2@Wnp+bnp);
// ST(bf16) = hn @ Wbig (Wbig mapping computed inline from We1/Wl1).
// ---------------------------------------------------------------------------
__global__ __launch_bounds__(256, 4)
void node_mlp_k(const unsigned* __restrict__ h1b, const float* __restrict__ aggh1,
                const float* __restrict__ W2s, const float* __restrict__ W2n,
                const float* __restrict__ b2, const float* __restrict__ Wnp,
                const float* __restrict__ bnp, const float* __restrict__ We1,
                const float* __restrict__ Wl1, unsigned short* __restrict__ ST, int N) {
    __shared__ __align__(16) float hT[64][68];
    __shared__ __align__(16) float wt[64][64];
    const int t = threadIdx.x;
    const int m0 = blockIdx.x * 64;
    const int cr = (t & 15) << 2, rr = (t >> 4) << 2;
    float acc[4][4] = {};

    // phase A1: self term from bf16 h1
#pragma unroll
    for (int it = 0; it < 8; ++it) {
        int u = it * 256 + t;
        int m = u >> 5, p = u & 31;
        int row = m0 + m;
        unsigned v = (row < N) ? h1b[(size_t)row * 32 + p] : 0u;
        hT[2 * p][m] = bflo(v);
        hT[2 * p + 1][m] = bfhi(v);
    }
#pragma unroll
    for (int it = 0; it < 16; ++it) {
        int k = it * 4 + (t >> 6), c = t & 63;
        wt[k][c] = W2s[k * 64 + c];
    }
    __syncthreads();
    mac64(hT, wt, rr, cr, acc);
    __syncthreads();

    // phase A2: neighbor term (fp32 aggh1)
#pragma unroll
    for (int it = 0; it < 16; ++it) {
        int m = it * 4 + (t >> 6), k = t & 63, row = m0 + m;
        hT[k][m] = (row < N) ? aggh1[(size_t)row * 64 + k] : 0.f;
    }
#pragma unroll
    for (int it = 0; it < 16; ++it) {
        int k = it * 4 + (t >> 6), c = t & 63;
        wt[k][c] = W2n[k * 64 + c];
    }
    __syncthreads();
    mac64(hT, wt, rr, cr, acc);
    __syncthreads();

    // h2 -> hT (transposed), wt <- Wnp
#pragma unroll
    for (int i = 0; i < 4; ++i)
#pragma unroll
        for (int q = 0; q < 4; ++q)
            hT[cr + q][rr + i] = fmaxf(acc[i][q] + b2[cr + q], 0.f);
#pragma unroll
    for (int it = 0; it < 16; ++it) {
        int k = it * 4 + (t >> 6), c = t & 63;
        wt[k][c] = Wnp[k * 64 + c];
    }
    __syncthreads();
    float ac2[4][4] = {};
    mac64(hT, wt, rr, cr, ac2);
    __syncthreads();

    // hn -> hT (transposed)
#pragma unroll
    for (int i = 0; i < 4; ++i)
#pragma unroll
        for (int q = 0; q < 4; ++q)
            hT[cr + q][rr + i] = fmaxf(ac2[i][q] + bnp[cr + q], 0.f);
    __syncthreads();

    // 4 column phases of ST = hn @ Wbig (mapping inline)
    for (int cb = 0; cb < 4; ++cb) {
        if (cb) __syncthreads();
#pragma unroll
        for (int it = 0; it < 16; ++it) {
            int k = it * 4 + (t >> 6), c = t & 63;
            int cglob = cb * 64 + c;
            int half = cglob >> 7, cc = cglob & 127;
            int jj = cc >> 1, p = cc & 1;
            const float* W = p ? Wl1 : We1;
            wt[k][c] = W[(half * 64 + k) * 64 + jj];
        }
        __syncthreads();
        float ac3[4][4] = {};
        mac64(hT, wt, rr, cr, ac3);
#pragma unroll
        for (int i = 0; i < 4; ++i) {
            int row = m0 + rr + i;
            if (row >= N) continue;
            ushort4 pk;
            pk.x = f2bf(ac3[i][0]); pk.y = f2bf(ac3[i][1]);
            pk.z = f2bf(ac3[i][2]); pk.w = f2bf(ac3[i][3]);
            *(ushort4*)&ST[(size_t)row * 256 + cb * 64 + cr] = pk;
        }
    }
}

// ---------------------------------------------------------------------------
// Edge scorer: one wave per node, CSR order, 4 edges/wave x 16 lanes x 4 j.
// ST32[n*128 + c]: c<64 src pair (lo=We1,hi=Wl1) for j=c; c>=64 dst pair.
// Quarter g handles edge slot i+g; lane q covers j0=4q..4q+3 (uint4 load).
// ef rows scalar via readlane; reductions are 4-op DPP trees (no DS).
// ---------------------------------------------------------------------------
__global__ void edge_k(const int* __restrict__ off, const int2* __restrict__ csr,
                       const float* __restrict__ ef, const unsigned* __restrict__ ST32,
                       const float* __restrict__ We1, const float* __restrict__ be1,
                       const float* __restrict__ We2, const float* __restrict__ be2,
                       const float* __restrict__ Wl1, const float* __restrict__ bl1,
                       const float* __restrict__ Wl2, const float* __restrict__ bl2,
                       float* __restrict__ out, int N) {
    int n = blockIdx.x * 4 + (threadIdx.x >> 6);
    if (n >= N) return;
    const int l = threadIdx.x & 63;
    const int g = l >> 4;            // edge slot within the 4-edge group
    const int q = l & 15;            // j-group
    const int j0 = q << 2;
    int s0 = off[n], s1 = off[n + 1];
    if (s0 >= s1) return;

    float4 wet[5], wlt[5];
#pragma unroll
    for (int k = 0; k < 5; ++k) {
        wet[k] = *(const float4*)&We1[(128 + k) * 64 + j0];
        wlt[k] = *(const float4*)&Wl1[(128 + k) * 64 + j0];
    }
    const float4 vbe1 = *(const float4*)&be1[j0];
    const float4 vwe2 = *(const float4*)&We2[j0];
    const float4 vbl1 = *(const float4*)&bl1[j0];
    const float4 vwl2 = *(const float4*)&Wl2[j0];
    const float vbe2 = be2[0], vbl2 = bl2[0];

    // dst part (per-node, loaded once): 4 packed pairs
    uint4 pw = *(const uint4*)&ST32[(size_t)n * 128 + 64 + j0];
    const float4 tb = {bflo(pw.x) + vbe1.x, bflo(pw.y) + vbe1.y,
                       bflo(pw.z) + vbe1.z, bflo(pw.w) + vbe1.w};
    const float4 ub = {bfhi(pw.x), bfhi(pw.y), bfhi(pw.z), bfhi(pw.w)};

    const bool gb1 = (g & 1), gb2 = (g & 2);

    for (int i = s0; i < s1; i += 4) {
        int ii = i + g;
        bool act = ii < s1;
        int2 se = csr[act ? ii : s0];                 // quarter-uniform
        uint4 sw = *(const uint4*)&ST32[(size_t)se.x * 128 + j0];
        float4 t4 = {bflo(sw.x) + tb.x, bflo(sw.y) + tb.y,
                     bflo(sw.z) + tb.z, bflo(sw.w) + tb.w};
        float4 u4 = {bfhi(sw.x) + ub.x, bfhi(sw.y) + ub.y,
                     bfhi(sw.z) + ub.z, bfhi(sw.w) + ub.w};
        // scalar ef rows for the 4 edges
        int e0 = __builtin_amdgcn_readlane(se.y, 0);
        int e1 = __builtin_amdgcn_readlane(se.y, 16);
        int e2 = __builtin_amdgcn_readlane(se.y, 32);
        int e3 = __builtin_amdgcn_readlane(se.y, 48);
        const float* p0 = ef + (size_t)e0 * 5;
        const float* p1 = ef + (size_t)e1 * 5;
        const float* p2 = ef + (size_t)e2 * 5;
        const float* p3 = ef + (size_t)e3 * 5;
#pragma unroll
        for (int k = 0; k < 5; ++k) {
            float a01 = gb1 ? p1[k] : p0[k];
            float a23 = gb1 ? p3[k] : p2[k];
            float ek  = gb2 ? a23 : a01;
            t4.x = fmaf(ek, wet[k].x, t4.x); t4.y = fmaf(ek, wet[k].y, t4.y);
            t4.z = fmaf(ek, wet[k].z, t4.z); t4.w = fmaf(ek, wet[k].w, t4.w);
            u4.x = fmaf(ek, wlt[k].x, u4.x); u4.y = fmaf(ek, wlt[k].y, u4.y);
            u4.z = fmaf(ek, wlt[k].z, u4.z); u4.w = fmaf(ek, wlt[k].w, u4.w);
        }
        float z = fast_tanh(t4.x) * vwe2.x + fast_tanh(t4.y) * vwe2.y
                + fast_tanh(t4.z) * vwe2.z + fast_tanh(t4.w) * vwe2.w;
        z = dpp_sum16(z);
        float w = fast_sigmoid(z + vbe2);
        float o = fmaxf(fmaf(w, u4.x, vbl1.x), 0.f) * vwl2.x
                + fmaxf(fmaf(w, u4.y, vbl1.y), 0.f) * vwl2.y
                + fmaxf(fmaf(w, u4.z, vbl1.z), 0.f) * vwl2.z
                + fmaxf(fmaf(w, u4.w, vbl1.w), 0.f) * vwl2.w;
        o = dpp_sum16(o);
        if (q == 0 && act) out[se.y] = o + vbl2;      // lanes 0,16,32,48
    }
}

extern "C" void kernel_launch(void* const* d_in, const int* in_sizes, int n_in,
                              void* d_out, int out_size, void* d_ws, size_t ws_size,
                              hipStream_t stream) {
    const float* nf  = (const float*)d_in[0];
    const float* ef  = (const float*)d_in[1];
    const int*   src = (const int*)d_in[2];
    const int*   dst = (const int*)d_in[3];
    const float* W1s = (const float*)d_in[4];
    const float* W1n = (const float*)d_in[5];
    const float* b1  = (const float*)d_in[6];
    const float* W2s = (const float*)d_in[7];
    const float* W2n = (const float*)d_in[8];
    const float* b2  = (const float*)d_in[9];
    const float* Wnp = (const float*)d_in[10];
    const float* bnp = (const float*)d_in[11];
    const float* We1 = (const float*)d_in[12];
    const float* be1 = (const float*)d_in[13];
    const float* We2 = (const float*)d_in[14];
    const float* be2 = (const float*)d_in[15];
    const float* Wl1 = (const float*)d_in[16];
    const float* bl1 = (const float*)d_in[17];
    const float* Wl2 = (const float*)d_in[18];
    const float* bl2 = (const float*)d_in[19];

    const int N = in_sizes[0] / 4;
    const int E = in_sizes[2];

    // ws layout (float units), peak ~274N = ~110 MB (proven budget ~128 MB):
    //  ST(bf16): [0, 128N)      written by node_mlp, read by edge_k
    //  aggh1:    [128N, 192N)
    //  h1b:      [192N, 224N)   packed bf16 h1 (uint[32N])
    //  csr:      [224N, 256N)   int2[E]
    //  rank:     [256N, 272N)   int[E]
    //  deg:      [272N, 273N)   int[N]
    //  off:      [273N, 274N)+1 int[N+1]
    //  bsum:     off+N+1        int[512]
    float* wsf = (float*)d_ws;
    unsigned short* ST = (unsigned short*)wsf;
    float* aggh1 = wsf + (size_t)128 * N;
    unsigned* h1b = (unsigned*)(wsf + (size_t)192 * N);
    int2* csr  = (int2*)(wsf + (size_t)224 * N);
    int*  rank = (int*)(wsf + (size_t)256 * N);
    int*  deg  = (int*)(wsf + (size_t)272 * N);
    int*  off  = deg + N;
    int*  bsum = off + N + 1;
    float* out = (float*)d_out;

    const int nblkN1 = (N + 255) / 256;
    const int nblkE  = (E + 255) / 256;
    const int nblkNw = (N + 3) / 4;
    const int gemmx  = (N + 63) / 64;

    // CSR build: single atomic pass + scan + atomic-free fill
    hipMemsetAsync(deg, 0, (size_t)N * sizeof(int), stream);
    rank_k<<<nblkE, 256, 0, stream>>>(dst, deg, rank, E);
    scan1_k<<<nblkN1, 256, 0, stream>>>(deg, off, bsum, N);
    scan2_k<<<1, 512, 0, stream>>>(bsum, nblkN1);
    scan3_k<<<nblkN1, 256, 0, stream>>>(off, bsum, N, E);
    fill2_k<<<nblkE, 256, 0, stream>>>(src, dst, off, rank, csr, E);

    // layer 1 (fused aggregate + h1, bf16 out)
    aggh1f_k<<<nblkNw, 256, 0, stream>>>(off, csr, nf, W1s, W1n, b1,
                                         (unsigned short*)h1b, N);

    // layer 2 gather
    gatherh1_k<<<nblkNw, 256, 0, stream>>>(off, csr, h1b, aggh1, N);

    // fused node MLP -> bf16 ST table
    node_mlp_k<<<gemmx, 256, 0, stream>>>(h1b, aggh1, W2s, W2n, b2,
                                          Wnp, bnp, We1, Wl1, ST, N);

    // per-edge scoring
    edge_k<<<nblkNw, 256, 0, stream>>>(off, csr, ef, (const unsigned*)ST,
                                       We1, be1, We2, be2, Wl1, bl1, Wl2, bl2,
                                       out, N);
}